// Round 11
// baseline (4459.473 us; speedup 1.0000x reference)
//
#include <hip/hip_runtime.h>
#include <stdint.h>

#define NPOINT 1024
#define NSAMPLE 32
#define NB 16
#define NN 4096
#define BN_EPS 1e-5
#define NPIX (NB*NPOINT*NSAMPLE)   // 524288 pixels (b,s,k)

// f32, no FMA contraction (FPS only — verified index-exact vs reference via out0).
__device__ __forceinline__ float sqdist3(float dx, float dy, float dz) {
  #pragma clang fp contract(off)
  float a = dx*dx; float b = dy*dy; float c = dz*dz;
  return (a + b) + c;
}

__global__ void zero_stats_kernel(double* __restrict__ s) {
  int i = blockIdx.x * 256 + threadIdx.x;
  if (i < 768) s[i] = 0.0;
}

// ---------------- FPS: ONE WAVE per batch, 64 pts/lane, ZERO barriers -----------
// Single-wave LDS use needs no __syncthreads (in-order per-wave DS pipeline).
__global__ __launch_bounds__(64, 1) void fps_kernel(
    const float* __restrict__ xyz, int* __restrict__ cents_g) {
  __shared__ float xs[NN], ys[NN], zs[NN];
  const int b = blockIdx.x;
  const int lane = threadIdx.x;           // 0..63
  const float* base = xyz + (size_t)b * NN * 3;
  for (int i = lane; i < NN; i += 64) {
    xs[i] = base[3*i+0];
    ys[i] = base[3*i+1];
    zs[i] = base[3*i+2];
  }
  float px[64], py[64], pz[64], dist[64];
  #pragma unroll
  for (int i = 0; i < 64; i++) {
    int j = i*64 + lane;
    px[i] = xs[j]; py[i] = ys[j]; pz[i] = zs[j];
    dist[i] = 1e10f;
  }
  int far = 0;
  for (int it = 0; it < NPOINT; it++) {
    if (lane == 0) cents_g[b*NPOINT + it] = far;   // carry BEFORE update (lax.scan)
    float cx = xs[far], cy = ys[far], cz = zs[far];  // LDS broadcast read
    float bv = -1.0f; int bj = 0x7fffffff;
    #pragma unroll
    for (int i = 0; i < 64; i++) {
      float d = sqdist3(px[i]-cx, py[i]-cy, pz[i]-cz);
      float nd = fminf(dist[i], d);
      dist[i] = nd;
      int j = i*64 + lane;
      if (nd > bv) { bv = nd; bj = j; }   // ascending j in-thread: > keeps first
    }
    // butterfly all-reduce: lexicographic max on (v, -j) — all lanes converge
    #pragma unroll
    for (int off = 32; off > 0; off >>= 1) {
      float ov = __shfl_xor(bv, off);
      int   oj = __shfl_xor(bj, off);
      if (ov > bv || (ov == bv && oj < bj)) { bv = ov; bj = oj; }
    }
    far = bj;
  }
}

// ---------------- ball query: F64 distances (the proven discrete-exact fix) ------
__global__ __launch_bounds__(256) void ballquery_kernel(
    const float* __restrict__ xyz, const int* __restrict__ cents_g,
    int* __restrict__ idx) {
  const int w = blockIdx.x * 4 + (threadIdx.x >> 6);
  const int lane = threadIdx.x & 63;
  const int b = w >> 10;
  const double RR = 0.2 * 0.2;
  const int cj = cents_g[w] & (NN-1);
  const float* cptr = xyz + ((size_t)b * NN + cj) * 3;
  const double cx = (double)cptr[0], cy = (double)cptr[1], cz = (double)cptr[2];
  const double cn = cx*cx + cy*cy + cz*cz;
  const float* base = xyz + (size_t)b * NN * 3;
  int* out = idx + (size_t)w * NSAMPLE;
  int have = 0, firstj = 0;
  for (int j0 = 0; j0 < NN; j0 += 64) {
    int j = j0 + lane;
    double x = (double)base[3*j+0];
    double y = (double)base[3*j+1];
    double z = (double)base[3*j+2];
    double pn = x*x + y*y + z*z;
    double d = -2.0*(cx*x + cy*y + cz*z) + cn + pn;
    bool pass = !(d > RR);
    unsigned long long m = __ballot(pass);
    int cnt = __popcll(m);
    if (have == 0 && cnt > 0) firstj = j0 + (__ffsll((unsigned long long)m) - 1);
    if (pass) {
      int pos = have + __popcll(m & ((1ull << lane) - 1ull));
      if (pos < NSAMPLE) out[pos] = j;
    }
    have += cnt;
    if (have >= NSAMPLE) break;
  }
  for (int k = have + lane; k < NSAMPLE; k += 64) out[k] = firstj;
}

// ---------------- fused pass (f32 GEMMs, f64 stats); optional Y1 cache -----------
// MODE 1: gather+gemm1 -> stats1 (+ store Y1 if provided)
// MODE 2: [CACHED: load Y1] bn1relu+gemm2 -> stats2
// MODE 3: [CACHED: load Y1] bn1relu+gemm2+bn2relu+gemm3 -> stats3 + min/max pools
template<int MODE, bool CACHED>
__global__ __launch_bounds__(256) void fused_pass(
    const float* __restrict__ xyz, const float* __restrict__ points,
    const int* __restrict__ cents_g, const int* __restrict__ idx,
    const float* __restrict__ w1, const float* __restrict__ b1,
    const float* __restrict__ w2, const float* __restrict__ b2,
    const float* __restrict__ w3, const float* __restrict__ b3,
    const double* __restrict__ aff1, const double* __restrict__ aff2,
    double* __restrict__ stats, float* __restrict__ pmax, float* __restrict__ pmin,
    float* __restrict__ Y1) {
  __shared__ float wbuf[67*64];
  __shared__ float xsm[67*68];
  __shared__ float ysm[64*68];
  __shared__ float bsm[64];
  __shared__ float sc1m[64], sh1m[64], sc2m[64], sh2m[64];
  const int t = threadIdx.x;
  const int pb = blockIdx.x * 64;
  const int tr = t & 15, tc = t >> 4;

  float acc2[4][4] = {};   // gemm2 result (MODE>=2)

  if constexpr (MODE == 1 || !CACHED) {
    // ---- stage-1 weights + gather ----
    for (int ii = t; ii < 67*64; ii += 256) {
      int oc = ii & 63, cc = ii >> 6;
      wbuf[cc*64 + oc] = w1[oc*67 + cc];
    }
    if (t < 64) {
      bsm[t] = b1[t];
      if (MODE >= 2) { sc1m[t] = (float)aff1[t]; sh1m[t] = (float)aff1[128+t]; }
      if (MODE >= 3) { sc2m[t] = (float)aff2[t]; sh2m[t] = (float)aff2[128+t]; }
    }
    {
      const int pxl = t >> 2, q = t & 3;
      const int p = pb + pxl;
      const int bs = p >> 5;
      const int b  = p >> 15;
      const int j  = idx[p] & (NN-1);
      const float4* prow = (const float4*)(points + ((size_t)b * NN + j) * 64);
      #pragma unroll
      for (int u = 0; u < 4; u++) {
        float4 v = prow[q*4 + u];
        int c0 = 3 + q*16 + u*4;
        xsm[(c0+0)*68 + pxl] = v.x;
        xsm[(c0+1)*68 + pxl] = v.y;
        xsm[(c0+2)*68 + pxl] = v.z;
        xsm[(c0+3)*68 + pxl] = v.w;
      }
      if (q == 0) {
        const float* xr = xyz + ((size_t)b * NN + j) * 3;
        const int cj = cents_g[bs] & (NN-1);
        const float* ce = xyz + ((size_t)b * NN + cj) * 3;
        xsm[0*68 + pxl] = xr[0] - ce[0];
        xsm[1*68 + pxl] = xr[1] - ce[1];
        xsm[2*68 + pxl] = xr[2] - ce[2];
      }
    }
    __syncthreads();
    // ---- gemm1 (67 -> 64) f32 ----
    float acc[4][4] = {};
    for (int cc = 0; cc < 67; cc++) {
      float4 xv = *(const float4*)&xsm[cc*68 + 4*tr];
      float4 wv = *(const float4*)&wbuf[cc*64 + 4*tc];
      float xa[4] = {xv.x, xv.y, xv.z, xv.w};
      float wa[4] = {wv.x, wv.y, wv.z, wv.w};
      #pragma unroll
      for (int i = 0; i < 4; i++)
        #pragma unroll
        for (int jj = 0; jj < 4; jj++) acc[i][jj] += xa[i]*wa[jj];
    }
    if constexpr (MODE == 1) {
      // optional Y1 store (f32, channel-major, coalesced)
      if (Y1 != nullptr) {
        #pragma unroll
        for (int jj = 0; jj < 4; jj++) {
          int oc = 4*tc + jj;
          float bb = bsm[oc];
          float4 yv = make_float4(acc[0][jj]+bb, acc[1][jj]+bb,
                                  acc[2][jj]+bb, acc[3][jj]+bb);
          *(float4*)(Y1 + (size_t)oc*NPIX + pb + 4*tr) = yv;
        }
      }
      double s1[4] = {0,0,0,0}, s2[4] = {0,0,0,0};
      #pragma unroll
      for (int jj = 0; jj < 4; jj++) {
        float bb = bsm[4*tc+jj];
        #pragma unroll
        for (int i = 0; i < 4; i++) {
          double yd = (double)(acc[i][jj] + bb);
          s1[jj] += yd; s2[jj] += yd*yd;
        }
      }
      #pragma unroll
      for (int off = 8; off > 0; off >>= 1)
        #pragma unroll
        for (int jj = 0; jj < 4; jj++) {
          s1[jj] += __shfl_down(s1[jj], off, 16);
          s2[jj] += __shfl_down(s2[jj], off, 16);
        }
      if (tr == 0)
        #pragma unroll
        for (int jj = 0; jj < 4; jj++) {
          atomicAdd(&stats[4*tc+jj],       s1[jj]);
          atomicAdd(&stats[128 + 4*tc+jj], s2[jj]);
        }
      return;
    } else {
      // ---- bn1 + relu -> ysm ----
      #pragma unroll
      for (int jj = 0; jj < 4; jj++) {
        int oc = 4*tc + jj;
        float bb = bsm[oc], sc = sc1m[oc], sh = sh1m[oc];
        float r[4];
        #pragma unroll
        for (int i = 0; i < 4; i++) r[i] = fmaxf((acc[i][jj] + bb)*sc + sh, 0.f);
        *(float4*)&ysm[oc*68 + 4*tr] = make_float4(r[0], r[1], r[2], r[3]);
      }
      __syncthreads();
      // ---- stage-2 weights ----
      for (int ii = t; ii < 4096; ii += 256) {
        int oc = ii & 63, cc = ii >> 6;
        wbuf[cc*64 + oc] = w2[oc*64 + cc];
      }
      if (t < 64) bsm[t] = b2[t];
      __syncthreads();
    }
  } else {
    // ---- CACHED (MODE>=2): w2 + Y1-load + bn1relu-on-load -> ysm ----
    for (int ii = t; ii < 4096; ii += 256) {
      int oc = ii & 63, cc = ii >> 6;
      wbuf[cc*64 + oc] = w2[oc*64 + cc];
    }
    if (t < 64) {
      bsm[t] = b2[t];
      if (MODE >= 3) { sc2m[t] = (float)aff2[t]; sh2m[t] = (float)aff2[128+t]; }
    }
    #pragma unroll
    for (int u = 0; u < 4; u++) {
      int fi = u*256 + t;
      int cch = fi >> 4, px4 = fi & 15;
      float4 v = *(const float4*)(Y1 + (size_t)cch*NPIX + pb + 4*px4);
      float sc = (float)aff1[cch], sh = (float)aff1[128+cch];  // global read: no LDS dep
      float4 r;
      r.x = fmaxf(v.x*sc+sh, 0.f); r.y = fmaxf(v.y*sc+sh, 0.f);
      r.z = fmaxf(v.z*sc+sh, 0.f); r.w = fmaxf(v.w*sc+sh, 0.f);
      *(float4*)&ysm[cch*68 + 4*px4] = r;
    }
    __syncthreads();
  }

  // ---- gemm2 (64 -> 64) f32 (ysm + wbuf(w2) + bsm(b2) ready, synced) ----
  for (int cc = 0; cc < 64; cc++) {
    float4 xv = *(const float4*)&ysm[cc*68 + 4*tr];
    float4 wv = *(const float4*)&wbuf[cc*64 + 4*tc];
    float xa[4] = {xv.x, xv.y, xv.z, xv.w};
    float wa[4] = {wv.x, wv.y, wv.z, wv.w};
    #pragma unroll
    for (int i = 0; i < 4; i++)
      #pragma unroll
      for (int jj = 0; jj < 4; jj++) acc2[i][jj] += xa[i]*wa[jj];
  }
  if constexpr (MODE == 2) {
    double s1[4] = {0,0,0,0}, s2[4] = {0,0,0,0};
    #pragma unroll
    for (int jj = 0; jj < 4; jj++) {
      float bb = bsm[4*tc+jj];
      #pragma unroll
      for (int i = 0; i < 4; i++) {
        double yd = (double)(acc2[i][jj] + bb);
        s1[jj] += yd; s2[jj] += yd*yd;
      }
    }
    #pragma unroll
    for (int off = 8; off > 0; off >>= 1)
      #pragma unroll
      for (int jj = 0; jj < 4; jj++) {
        s1[jj] += __shfl_down(s1[jj], off, 16);
        s2[jj] += __shfl_down(s2[jj], off, 16);
      }
    if (tr == 0)
      #pragma unroll
      for (int jj = 0; jj < 4; jj++) {
        atomicAdd(&stats[4*tc+jj],       s1[jj]);
        atomicAdd(&stats[128 + 4*tc+jj], s2[jj]);
      }
    return;
  }

  if constexpr (MODE == 3) {
    // ---- bn2 + relu -> xsm rows 0..63 ----
    #pragma unroll
    for (int jj = 0; jj < 4; jj++) {
      int oc = 4*tc + jj;
      float bb = bsm[oc], sc = sc2m[oc], sh = sh2m[oc];
      float r[4];
      #pragma unroll
      for (int i = 0; i < 4; i++) r[i] = fmaxf((acc2[i][jj] + bb)*sc + sh, 0.f);
      *(float4*)&xsm[oc*68 + 4*tr] = make_float4(r[0], r[1], r[2], r[3]);
    }
    __syncthreads();
    // ---- gemm3 (64 -> 128) two halves: stats + pre-bn3 min/max pools ----
    for (int h = 0; h < 2; h++) {
      for (int ii = t; ii < 4096; ii += 256) {
        int oc = ii & 63, cc = ii >> 6;
        wbuf[cc*64 + oc] = w3[(h*64 + oc)*64 + cc];
      }
      if (t < 64) bsm[t] = b3[h*64 + t];
      __syncthreads();
      float acc3[4][4] = {};
      for (int cc = 0; cc < 64; cc++) {
        float4 xv = *(const float4*)&xsm[cc*68 + 4*tr];
        float4 wv = *(const float4*)&wbuf[cc*64 + 4*tc];
        float xa[4] = {xv.x, xv.y, xv.z, xv.w};
        float wa[4] = {wv.x, wv.y, wv.z, wv.w};
        #pragma unroll
        for (int i = 0; i < 4; i++)
          #pragma unroll
          for (int jj = 0; jj < 4; jj++) acc3[i][jj] += xa[i]*wa[jj];
      }
      double s1[4] = {0,0,0,0}, s2[4] = {0,0,0,0};
      float pmx[4], pmn[4];
      #pragma unroll
      for (int jj = 0; jj < 4; jj++) { pmx[jj] = -3.4e38f; pmn[jj] = 3.4e38f; }
      #pragma unroll
      for (int jj = 0; jj < 4; jj++) {
        float bb = bsm[4*tc+jj];
        #pragma unroll
        for (int i = 0; i < 4; i++) {
          float y = acc3[i][jj] + bb;
          double yd = (double)y;
          s1[jj] += yd; s2[jj] += yd*yd;
          pmx[jj] = fmaxf(pmx[jj], y); pmn[jj] = fminf(pmn[jj], y);
        }
      }
      #pragma unroll
      for (int off = 8; off > 0; off >>= 1)
        #pragma unroll
        for (int jj = 0; jj < 4; jj++) {
          s1[jj] += __shfl_down(s1[jj], off, 16);
          s2[jj] += __shfl_down(s2[jj], off, 16);
        }
      if (tr == 0)
        #pragma unroll
        for (int jj = 0; jj < 4; jj++) {
          atomicAdd(&stats[h*64 + 4*tc+jj],       s1[jj]);
          atomicAdd(&stats[128 + h*64 + 4*tc+jj], s2[jj]);
        }
      #pragma unroll
      for (int off = 4; off > 0; off >>= 1)
        #pragma unroll
        for (int jj = 0; jj < 4; jj++) {
          pmx[jj] = fmaxf(pmx[jj], __shfl_down(pmx[jj], off, 8));
          pmn[jj] = fminf(pmn[jj], __shfl_down(pmn[jj], off, 8));
        }
      if ((tr & 7) == 0) {
        int bs = (pb >> 5) + (tr >> 3);
        size_t ob = (size_t)bs*128 + h*64 + 4*tc;
        #pragma unroll
        for (int jj = 0; jj < 4; jj++) {
          pmax[ob + jj] = pmx[jj];
          pmin[ob + jj] = pmn[jj];
        }
      }
      __syncthreads();
    }
  }
}

// ---------------- BN finalize: f64 affine params ---------------------------------
__global__ void finalize_kernel(const double* __restrict__ stats,
                                const float* __restrict__ g,
                                const float* __restrict__ beta,
                                double* __restrict__ aff, int nch) {
  int c = threadIdx.x;
  if (c < nch) {
    const double invN = 1.0 / (double)NPIX;
    double mean = stats[c] * invN;
    double var  = stats[128+c] * invN - mean*mean;
    var = var > 0.0 ? var : 0.0;
    double r  = 1.0 / sqrt(var + BN_EPS);
    double sc = (double)g[c] * r;
    aff[c]       = sc;
    aff[128 + c] = (double)beta[c] - mean*sc;
  }
}

// ---------------- epilogue: bn3+relu on pooled extremum (monotone trick) ---------
__global__ __launch_bounds__(256) void out_kernel(
    const float* __restrict__ pmax, const float* __restrict__ pmin,
    const double* __restrict__ aff3, float* __restrict__ out_np) {
  int i = blockIdx.x * 256 + threadIdx.x;   // [0, 2097152)
  int oc = i & 127;
  double sc = aff3[oc], sh = aff3[128+oc];
  double v = (sc >= 0.0) ? (double)pmax[i] : (double)pmin[i];
  double y = v*sc + sh;
  out_np[i] = (float)(y > 0.0 ? y : 0.0);
}

// ---------------- sole writer of new_xyz ------------------------------------------
__global__ __launch_bounds__(1024) void write_newxyz_kernel(
    const float* __restrict__ xyz, const int* __restrict__ cents_g,
    float* __restrict__ out) {
  int i = blockIdx.x * 1024 + threadIdx.x;    // [0, 16384)
  int b = i >> 10;
  int j = cents_g[i] & (NN-1);
  const float* src = xyz + ((size_t)b * NN + j) * 3;
  size_t o = (size_t)i * 3;
  out[o+0] = src[0];
  out[o+1] = src[1];
  out[o+2] = src[2];
}

extern "C" void kernel_launch(void* const* d_in, const int* in_sizes, int n_in,
                              void* d_out, int out_size, void* d_ws, size_t ws_size,
                              hipStream_t stream) {
  const float* xyz    = (const float*)d_in[0];
  const float* points = (const float*)d_in[1];
  const float* w1  = (const float*)d_in[2];
  const float* b1  = (const float*)d_in[3];
  const float* g1  = (const float*)d_in[4];
  const float* be1 = (const float*)d_in[5];
  const float* w2  = (const float*)d_in[6];
  const float* b2  = (const float*)d_in[7];
  const float* g2  = (const float*)d_in[8];
  const float* be2 = (const float*)d_in[9];
  const float* w3  = (const float*)d_in[10];
  const float* b3  = (const float*)d_in[11];
  const float* g3  = (const float*)d_in[12];
  const float* be3 = (const float*)d_in[13];

  // workspace: base ~19 MB (+134 MB Y1 cache when ws_size permits)
  char* ws = (char*)d_ws;
  double* stats = (double*)(ws + 0);         // 768 f64
  double* aff   = (double*)(ws + 8192);      // 768 f64
  int*    cents = (int*)  (ws + 16384);      // 16384 i32
  int*    idx   = (int*)  (ws + 81920);      // 524288 i32
  float*  pmax  = (float*)(ws + 2179072);    // 2097152 f32
  float*  pmin  = (float*)(ws + 10567680);   // 2097152 f32
  const size_t BASE = 18956288ull;
  const size_t Y1SZ = (size_t)64 * NPIX * sizeof(float);   // 134217728
  const bool cached = (ws_size >= BASE + Y1SZ);
  float* Y1 = cached ? (float*)(ws + BASE) : nullptr;
  float* out_xyz = (float*)d_out;                          // f32 new_xyz
  float* out_np  = (float*)d_out + (size_t)NB*NPOINT*3;    // f32 new_points

  zero_stats_kernel <<<3,    256, 0, stream>>>(stats);
  fps_kernel        <<<16,    64, 0, stream>>>(xyz, cents);
  ballquery_kernel  <<<4096, 256, 0, stream>>>(xyz, cents, idx);
  fused_pass<1,false><<<8192,256, 0, stream>>>(xyz, points, cents, idx, w1,b1,w2,b2,w3,b3,
                                               aff, aff+256, stats,       pmax, pmin, Y1);
  finalize_kernel   <<<1,    128, 0, stream>>>(stats,     g1, be1, aff,     64);
  if (cached) {
    fused_pass<2,true><<<8192,256,0, stream>>>(xyz, points, cents, idx, w1,b1,w2,b2,w3,b3,
                                               aff, aff+256, stats + 256, pmax, pmin, Y1);
  } else {
    fused_pass<2,false><<<8192,256,0,stream>>>(xyz, points, cents, idx, w1,b1,w2,b2,w3,b3,
                                               aff, aff+256, stats + 256, pmax, pmin, nullptr);
  }
  finalize_kernel   <<<1,    128, 0, stream>>>(stats+256, g2, be2, aff+256, 64);
  if (cached) {
    fused_pass<3,true><<<8192,256,0, stream>>>(xyz, points, cents, idx, w1,b1,w2,b2,w3,b3,
                                               aff, aff+256, stats + 512, pmax, pmin, Y1);
  } else {
    fused_pass<3,false><<<8192,256,0,stream>>>(xyz, points, cents, idx, w1,b1,w2,b2,w3,b3,
                                               aff, aff+256, stats + 512, pmax, pmin, nullptr);
  }
  finalize_kernel   <<<1,    128, 0, stream>>>(stats+512, g3, be3, aff+512, 128);
  out_kernel        <<<8192, 256, 0, stream>>>(pmax, pmin, aff+512, out_np);
  write_newxyz_kernel<<<16, 1024, 0, stream>>>(xyz, cents, out_xyz);
}

// Round 12
// 3479.576 us; speedup vs baseline: 1.2816x; 1.2816x over previous
//
#include <hip/hip_runtime.h>
#include <stdint.h>

#define NPOINT 1024
#define NSAMPLE 32
#define NB 16
#define NN 4096
#define BN_EPS 1e-5
#define NPIX (NB*NPOINT*NSAMPLE)   // 524288 pixels (b,s,k)

// f32, no FMA contraction (FPS only — verified index-exact vs reference via out0).
__device__ __forceinline__ float sqdist3(float dx, float dy, float dz) {
  #pragma clang fp contract(off)
  float a = dx*dx; float b = dy*dy; float c = dz*dz;
  return (a + b) + c;
}

__global__ void zero_stats_kernel(double* __restrict__ s) {
  int i = blockIdx.x * 256 + threadIdx.x;
  if (i < 768) s[i] = 0.0;
}

// ---------------- FPS: 256 thr x 16 pts, 1 barrier/iter (R10 proven: 1147us) ----
__global__ __launch_bounds__(256) void fps_kernel(
    const float* __restrict__ xyz, int* __restrict__ cents_g) {
  __shared__ float xs[NN], ys[NN], zs[NN];
  __shared__ float rv[2][4];
  __shared__ int   rj[2][4];
  const int b = blockIdx.x;
  const int t = threadIdx.x;
  const float* base = xyz + (size_t)b * NN * 3;
  for (int i = t; i < NN; i += 256) {
    xs[i] = base[3*i+0];
    ys[i] = base[3*i+1];
    zs[i] = base[3*i+2];
  }
  __syncthreads();
  float px[16], py[16], pz[16], dist[16];
  #pragma unroll
  for (int i = 0; i < 16; i++) {
    int j = i*256 + t;
    px[i] = xs[j]; py[i] = ys[j]; pz[i] = zs[j];
    dist[i] = 1e10f;
  }
  const int lane = t & 63, wid = t >> 6;
  int far = 0;
  for (int it = 0; it < NPOINT; it++) {
    if (t == 0) cents_g[b*NPOINT + it] = far;   // carry BEFORE update, like lax.scan
    float cx = xs[far], cy = ys[far], cz = zs[far];
    float bv = -1.0f; int bj = 0x7fffffff;
    #pragma unroll
    for (int i = 0; i < 16; i++) {
      float d = sqdist3(px[i]-cx, py[i]-cy, pz[i]-cz);
      float nd = fminf(dist[i], d);
      dist[i] = nd;
      int j = i*256 + t;
      if (nd > bv) { bv = nd; bj = j; }   // ascending j within thread: > keeps first
    }
    #pragma unroll
    for (int off = 32; off > 0; off >>= 1) {
      float ov = __shfl_down(bv, off);
      int   oj = __shfl_down(bj, off);
      if (ov > bv || (ov == bv && oj < bj)) { bv = ov; bj = oj; }
    }
    const int p = it & 1;
    if (lane == 0) { rv[p][wid] = bv; rj[p][wid] = bj; }
    __syncthreads();
    // all threads reduce the 4 wave results redundantly; parity buffer means the
    // next iteration's writes can't race this read (no 2nd barrier needed)
    float v = rv[p][0]; int jx = rj[p][0];
    #pragma unroll
    for (int w = 1; w < 4; w++) {
      if (rv[p][w] > v || (rv[p][w] == v && rj[p][w] < jx)) { v = rv[p][w]; jx = rj[p][w]; }
    }
    far = jx;
  }
}

// ---------------- ball query: F64 distances (the proven discrete-exact fix) ------
__global__ __launch_bounds__(256) void ballquery_kernel(
    const float* __restrict__ xyz, const int* __restrict__ cents_g,
    int* __restrict__ idx) {
  const int w = blockIdx.x * 4 + (threadIdx.x >> 6);
  const int lane = threadIdx.x & 63;
  const int b = w >> 10;
  const double RR = 0.2 * 0.2;
  const int cj = cents_g[w] & (NN-1);
  const float* cptr = xyz + ((size_t)b * NN + cj) * 3;
  const double cx = (double)cptr[0], cy = (double)cptr[1], cz = (double)cptr[2];
  const double cn = cx*cx + cy*cy + cz*cz;
  const float* base = xyz + (size_t)b * NN * 3;
  int* out = idx + (size_t)w * NSAMPLE;
  int have = 0, firstj = 0;
  for (int j0 = 0; j0 < NN; j0 += 64) {
    int j = j0 + lane;
    double x = (double)base[3*j+0];
    double y = (double)base[3*j+1];
    double z = (double)base[3*j+2];
    double pn = x*x + y*y + z*z;
    double d = -2.0*(cx*x + cy*y + cz*z) + cn + pn;
    bool pass = !(d > RR);
    unsigned long long m = __ballot(pass);
    int cnt = __popcll(m);
    if (have == 0 && cnt > 0) firstj = j0 + (__ffsll((unsigned long long)m) - 1);
    if (pass) {
      int pos = have + __popcll(m & ((1ull << lane) - 1ull));
      if (pos < NSAMPLE) out[pos] = j;
    }
    have += cnt;
    if (have >= NSAMPLE) break;
  }
  for (int k = have + lane; k < NSAMPLE; k += 64) out[k] = firstj;
}

// ---------------- fused pass (f32 GEMMs, f64 stats); optional Y1 cache -----------
// MODE 1: gather+gemm1 -> stats1 (+ store Y1 if provided)
// MODE 2: [CACHED: load Y1] bn1relu+gemm2 -> stats2
// MODE 3: [CACHED: load Y1] bn1relu+gemm2+bn2relu+gemm3 -> stats3 + min/max pools
template<int MODE, bool CACHED>
__global__ __launch_bounds__(256) void fused_pass(
    const float* __restrict__ xyz, const float* __restrict__ points,
    const int* __restrict__ cents_g, const int* __restrict__ idx,
    const float* __restrict__ w1, const float* __restrict__ b1,
    const float* __restrict__ w2, const float* __restrict__ b2,
    const float* __restrict__ w3, const float* __restrict__ b3,
    const double* __restrict__ aff1, const double* __restrict__ aff2,
    double* __restrict__ stats, float* __restrict__ pmax, float* __restrict__ pmin,
    float* __restrict__ Y1) {
  __shared__ float wbuf[67*64];
  __shared__ float xsm[67*68];
  __shared__ float ysm[64*68];
  __shared__ float bsm[64];
  __shared__ float sc1m[64], sh1m[64], sc2m[64], sh2m[64];
  const int t = threadIdx.x;
  const int pb = blockIdx.x * 64;
  const int tr = t & 15, tc = t >> 4;

  float acc2[4][4] = {};   // gemm2 result (MODE>=2)

  if constexpr (MODE == 1 || !CACHED) {
    for (int ii = t; ii < 67*64; ii += 256) {
      int oc = ii & 63, cc = ii >> 6;
      wbuf[cc*64 + oc] = w1[oc*67 + cc];
    }
    if (t < 64) {
      bsm[t] = b1[t];
      if (MODE >= 2) { sc1m[t] = (float)aff1[t]; sh1m[t] = (float)aff1[128+t]; }
      if (MODE >= 3) { sc2m[t] = (float)aff2[t]; sh2m[t] = (float)aff2[128+t]; }
    }
    {
      const int pxl = t >> 2, q = t & 3;
      const int p = pb + pxl;
      const int bs = p >> 5;
      const int b  = p >> 15;
      const int j  = idx[p] & (NN-1);
      const float4* prow = (const float4*)(points + ((size_t)b * NN + j) * 64);
      #pragma unroll
      for (int u = 0; u < 4; u++) {
        float4 v = prow[q*4 + u];
        int c0 = 3 + q*16 + u*4;
        xsm[(c0+0)*68 + pxl] = v.x;
        xsm[(c0+1)*68 + pxl] = v.y;
        xsm[(c0+2)*68 + pxl] = v.z;
        xsm[(c0+3)*68 + pxl] = v.w;
      }
      if (q == 0) {
        const float* xr = xyz + ((size_t)b * NN + j) * 3;
        const int cj = cents_g[bs] & (NN-1);
        const float* ce = xyz + ((size_t)b * NN + cj) * 3;
        xsm[0*68 + pxl] = xr[0] - ce[0];
        xsm[1*68 + pxl] = xr[1] - ce[1];
        xsm[2*68 + pxl] = xr[2] - ce[2];
      }
    }
    __syncthreads();
    // ---- gemm1 (67 -> 64) f32 ----
    float acc[4][4] = {};
    for (int cc = 0; cc < 67; cc++) {
      float4 xv = *(const float4*)&xsm[cc*68 + 4*tr];
      float4 wv = *(const float4*)&wbuf[cc*64 + 4*tc];
      float xa[4] = {xv.x, xv.y, xv.z, xv.w};
      float wa[4] = {wv.x, wv.y, wv.z, wv.w};
      #pragma unroll
      for (int i = 0; i < 4; i++)
        #pragma unroll
        for (int jj = 0; jj < 4; jj++) acc[i][jj] += xa[i]*wa[jj];
    }
    if constexpr (MODE == 1) {
      if (Y1 != nullptr) {
        #pragma unroll
        for (int jj = 0; jj < 4; jj++) {
          int oc = 4*tc + jj;
          float bb = bsm[oc];
          float4 yv = make_float4(acc[0][jj]+bb, acc[1][jj]+bb,
                                  acc[2][jj]+bb, acc[3][jj]+bb);
          *(float4*)(Y1 + (size_t)oc*NPIX + pb + 4*tr) = yv;
        }
      }
      double s1[4] = {0,0,0,0}, s2[4] = {0,0,0,0};
      #pragma unroll
      for (int jj = 0; jj < 4; jj++) {
        float bb = bsm[4*tc+jj];
        #pragma unroll
        for (int i = 0; i < 4; i++) {
          double yd = (double)(acc[i][jj] + bb);
          s1[jj] += yd; s2[jj] += yd*yd;
        }
      }
      #pragma unroll
      for (int off = 8; off > 0; off >>= 1)
        #pragma unroll
        for (int jj = 0; jj < 4; jj++) {
          s1[jj] += __shfl_down(s1[jj], off, 16);
          s2[jj] += __shfl_down(s2[jj], off, 16);
        }
      if (tr == 0)
        #pragma unroll
        for (int jj = 0; jj < 4; jj++) {
          atomicAdd(&stats[4*tc+jj],       s1[jj]);
          atomicAdd(&stats[128 + 4*tc+jj], s2[jj]);
        }
      return;
    } else {
      #pragma unroll
      for (int jj = 0; jj < 4; jj++) {
        int oc = 4*tc + jj;
        float bb = bsm[oc], sc = sc1m[oc], sh = sh1m[oc];
        float r[4];
        #pragma unroll
        for (int i = 0; i < 4; i++) r[i] = fmaxf((acc[i][jj] + bb)*sc + sh, 0.f);
        *(float4*)&ysm[oc*68 + 4*tr] = make_float4(r[0], r[1], r[2], r[3]);
      }
      __syncthreads();
      for (int ii = t; ii < 4096; ii += 256) {
        int oc = ii & 63, cc = ii >> 6;
        wbuf[cc*64 + oc] = w2[oc*64 + cc];
      }
      if (t < 64) bsm[t] = b2[t];
      __syncthreads();
    }
  } else {
    // ---- CACHED (MODE>=2): w2 + Y1-load + bn1relu-on-load -> ysm ----
    for (int ii = t; ii < 4096; ii += 256) {
      int oc = ii & 63, cc = ii >> 6;
      wbuf[cc*64 + oc] = w2[oc*64 + cc];
    }
    if (t < 64) {
      bsm[t] = b2[t];
      if (MODE >= 3) { sc2m[t] = (float)aff2[t]; sh2m[t] = (float)aff2[128+t]; }
    }
    #pragma unroll
    for (int u = 0; u < 4; u++) {
      int fi = u*256 + t;
      int cch = fi >> 4, px4 = fi & 15;
      float4 v = *(const float4*)(Y1 + (size_t)cch*NPIX + pb + 4*px4);
      float sc = (float)aff1[cch], sh = (float)aff1[128+cch];
      float4 r;
      r.x = fmaxf(v.x*sc+sh, 0.f); r.y = fmaxf(v.y*sc+sh, 0.f);
      r.z = fmaxf(v.z*sc+sh, 0.f); r.w = fmaxf(v.w*sc+sh, 0.f);
      *(float4*)&ysm[cch*68 + 4*px4] = r;
    }
    __syncthreads();
  }

  // ---- gemm2 (64 -> 64) f32 ----
  for (int cc = 0; cc < 64; cc++) {
    float4 xv = *(const float4*)&ysm[cc*68 + 4*tr];
    float4 wv = *(const float4*)&wbuf[cc*64 + 4*tc];
    float xa[4] = {xv.x, xv.y, xv.z, xv.w};
    float wa[4] = {wv.x, wv.y, wv.z, wv.w};
    #pragma unroll
    for (int i = 0; i < 4; i++)
      #pragma unroll
      for (int jj = 0; jj < 4; jj++) acc2[i][jj] += xa[i]*wa[jj];
  }
  if constexpr (MODE == 2) {
    double s1[4] = {0,0,0,0}, s2[4] = {0,0,0,0};
    #pragma unroll
    for (int jj = 0; jj < 4; jj++) {
      float bb = bsm[4*tc+jj];
      #pragma unroll
      for (int i = 0; i < 4; i++) {
        double yd = (double)(acc2[i][jj] + bb);
        s1[jj] += yd; s2[jj] += yd*yd;
      }
    }
    #pragma unroll
    for (int off = 8; off > 0; off >>= 1)
      #pragma unroll
      for (int jj = 0; jj < 4; jj++) {
        s1[jj] += __shfl_down(s1[jj], off, 16);
        s2[jj] += __shfl_down(s2[jj], off, 16);
      }
    if (tr == 0)
      #pragma unroll
      for (int jj = 0; jj < 4; jj++) {
        atomicAdd(&stats[4*tc+jj],       s1[jj]);
        atomicAdd(&stats[128 + 4*tc+jj], s2[jj]);
      }
    return;
  }

  if constexpr (MODE == 3) {
    #pragma unroll
    for (int jj = 0; jj < 4; jj++) {
      int oc = 4*tc + jj;
      float bb = bsm[oc], sc = sc2m[oc], sh = sh2m[oc];
      float r[4];
      #pragma unroll
      for (int i = 0; i < 4; i++) r[i] = fmaxf((acc2[i][jj] + bb)*sc + sh, 0.f);
      *(float4*)&xsm[oc*68 + 4*tr] = make_float4(r[0], r[1], r[2], r[3]);
    }
    __syncthreads();
    for (int h = 0; h < 2; h++) {
      for (int ii = t; ii < 4096; ii += 256) {
        int oc = ii & 63, cc = ii >> 6;
        wbuf[cc*64 + oc] = w3[(h*64 + oc)*64 + cc];
      }
      if (t < 64) bsm[t] = b3[h*64 + t];
      __syncthreads();
      float acc3[4][4] = {};
      for (int cc = 0; cc < 64; cc++) {
        float4 xv = *(const float4*)&xsm[cc*68 + 4*tr];
        float4 wv = *(const float4*)&wbuf[cc*64 + 4*tc];
        float xa[4] = {xv.x, xv.y, xv.z, xv.w};
        float wa[4] = {wv.x, wv.y, wv.z, wv.w};
        #pragma unroll
        for (int i = 0; i < 4; i++)
          #pragma unroll
          for (int jj = 0; jj < 4; jj++) acc3[i][jj] += xa[i]*wa[jj];
      }
      double s1[4] = {0,0,0,0}, s2[4] = {0,0,0,0};
      float pmx[4], pmn[4];
      #pragma unroll
      for (int jj = 0; jj < 4; jj++) { pmx[jj] = -3.4e38f; pmn[jj] = 3.4e38f; }
      #pragma unroll
      for (int jj = 0; jj < 4; jj++) {
        float bb = bsm[4*tc+jj];
        #pragma unroll
        for (int i = 0; i < 4; i++) {
          float y = acc3[i][jj] + bb;
          double yd = (double)y;
          s1[jj] += yd; s2[jj] += yd*yd;
          pmx[jj] = fmaxf(pmx[jj], y); pmn[jj] = fminf(pmn[jj], y);
        }
      }
      #pragma unroll
      for (int off = 8; off > 0; off >>= 1)
        #pragma unroll
        for (int jj = 0; jj < 4; jj++) {
          s1[jj] += __shfl_down(s1[jj], off, 16);
          s2[jj] += __shfl_down(s2[jj], off, 16);
        }
      if (tr == 0)
        #pragma unroll
        for (int jj = 0; jj < 4; jj++) {
          atomicAdd(&stats[h*64 + 4*tc+jj],       s1[jj]);
          atomicAdd(&stats[128 + h*64 + 4*tc+jj], s2[jj]);
        }
      #pragma unroll
      for (int off = 4; off > 0; off >>= 1)
        #pragma unroll
        for (int jj = 0; jj < 4; jj++) {
          pmx[jj] = fmaxf(pmx[jj], __shfl_down(pmx[jj], off, 8));
          pmn[jj] = fminf(pmn[jj], __shfl_down(pmn[jj], off, 8));
        }
      if ((tr & 7) == 0) {
        int bs = (pb >> 5) + (tr >> 3);
        size_t ob = (size_t)bs*128 + h*64 + 4*tc;
        #pragma unroll
        for (int jj = 0; jj < 4; jj++) {
          pmax[ob + jj] = pmx[jj];
          pmin[ob + jj] = pmn[jj];
        }
      }
      __syncthreads();
    }
  }
}

// ---------------- BN finalize: f64 affine params ---------------------------------
__global__ void finalize_kernel(const double* __restrict__ stats,
                                const float* __restrict__ g,
                                const float* __restrict__ beta,
                                double* __restrict__ aff, int nch) {
  int c = threadIdx.x;
  if (c < nch) {
    const double invN = 1.0 / (double)NPIX;
    double mean = stats[c] * invN;
    double var  = stats[128+c] * invN - mean*mean;
    var = var > 0.0 ? var : 0.0;
    double r  = 1.0 / sqrt(var + BN_EPS);
    double sc = (double)g[c] * r;
    aff[c]       = sc;
    aff[128 + c] = (double)beta[c] - mean*sc;
  }
}

// ---------------- epilogue: bn3+relu on pooled extremum (monotone trick) ---------
__global__ __launch_bounds__(256) void out_kernel(
    const float* __restrict__ pmax, const float* __restrict__ pmin,
    const double* __restrict__ aff3, float* __restrict__ out_np) {
  int i = blockIdx.x * 256 + threadIdx.x;   // [0, 2097152)
  int oc = i & 127;
  double sc = aff3[oc], sh = aff3[128+oc];
  double v = (sc >= 0.0) ? (double)pmax[i] : (double)pmin[i];
  double y = v*sc + sh;
  out_np[i] = (float)(y > 0.0 ? y : 0.0);
}

// ---------------- sole writer of new_xyz ------------------------------------------
__global__ __launch_bounds__(1024) void write_newxyz_kernel(
    const float* __restrict__ xyz, const int* __restrict__ cents_g,
    float* __restrict__ out) {
  int i = blockIdx.x * 1024 + threadIdx.x;    // [0, 16384)
  int b = i >> 10;
  int j = cents_g[i] & (NN-1);
  const float* src = xyz + ((size_t)b * NN + j) * 3;
  size_t o = (size_t)i * 3;
  out[o+0] = src[0];
  out[o+1] = src[1];
  out[o+2] = src[2];
}

extern "C" void kernel_launch(void* const* d_in, const int* in_sizes, int n_in,
                              void* d_out, int out_size, void* d_ws, size_t ws_size,
                              hipStream_t stream) {
  const float* xyz    = (const float*)d_in[0];
  const float* points = (const float*)d_in[1];
  const float* w1  = (const float*)d_in[2];
  const float* b1  = (const float*)d_in[3];
  const float* g1  = (const float*)d_in[4];
  const float* be1 = (const float*)d_in[5];
  const float* w2  = (const float*)d_in[6];
  const float* b2  = (const float*)d_in[7];
  const float* g2  = (const float*)d_in[8];
  const float* be2 = (const float*)d_in[9];
  const float* w3  = (const float*)d_in[10];
  const float* b3  = (const float*)d_in[11];
  const float* g3  = (const float*)d_in[12];
  const float* be3 = (const float*)d_in[13];

  // workspace: base ~19 MB (+134 MB Y1 cache when ws_size permits)
  char* ws = (char*)d_ws;
  double* stats = (double*)(ws + 0);         // 768 f64
  double* aff   = (double*)(ws + 8192);      // 768 f64
  int*    cents = (int*)  (ws + 16384);      // 16384 i32
  int*    idx   = (int*)  (ws + 81920);      // 524288 i32
  float*  pmax  = (float*)(ws + 2179072);    // 2097152 f32
  float*  pmin  = (float*)(ws + 10567680);   // 2097152 f32
  const size_t BASE = 18956288ull;
  const size_t Y1SZ = (size_t)64 * NPIX * sizeof(float);   // 134217728
  const bool cached = (ws_size >= BASE + Y1SZ);
  float* Y1 = cached ? (float*)(ws + BASE) : nullptr;
  float* out_xyz = (float*)d_out;                          // f32 new_xyz
  float* out_np  = (float*)d_out + (size_t)NB*NPOINT*3;    // f32 new_points

  zero_stats_kernel <<<3,    256, 0, stream>>>(stats);
  fps_kernel        <<<16,   256, 0, stream>>>(xyz, cents);
  ballquery_kernel  <<<4096, 256, 0, stream>>>(xyz, cents, idx);
  fused_pass<1,false><<<8192,256, 0, stream>>>(xyz, points, cents, idx, w1,b1,w2,b2,w3,b3,
                                               aff, aff+256, stats,       pmax, pmin, Y1);
  finalize_kernel   <<<1,    128, 0, stream>>>(stats,     g1, be1, aff,     64);
  if (cached) {
    fused_pass<2,true><<<8192,256,0, stream>>>(xyz, points, cents, idx, w1,b1,w2,b2,w3,b3,
                                               aff, aff+256, stats + 256, pmax, pmin, Y1);
  } else {
    fused_pass<2,false><<<8192,256,0,stream>>>(xyz, points, cents, idx, w1,b1,w2,b2,w3,b3,
                                               aff, aff+256, stats + 256, pmax, pmin, nullptr);
  }
  finalize_kernel   <<<1,    128, 0, stream>>>(stats+256, g2, be2, aff+256, 64);
  if (cached) {
    fused_pass<3,true><<<8192,256,0, stream>>>(xyz, points, cents, idx, w1,b1,w2,b2,w3,b3,
                                               aff, aff+256, stats + 512, pmax, pmin, Y1);
  } else {
    fused_pass<3,false><<<8192,256,0,stream>>>(xyz, points, cents, idx, w1,b1,w2,b2,w3,b3,
                                               aff, aff+256, stats + 512, pmax, pmin, nullptr);
  }
  finalize_kernel   <<<1,    128, 0, stream>>>(stats+512, g3, be3, aff+512, 128);
  out_kernel        <<<8192, 256, 0, stream>>>(pmax, pmin, aff+512, out_np);
  write_newxyz_kernel<<<16, 1024, 0, stream>>>(xyz, cents, out_xyz);
}